// Round 21
// baseline (4936.074 us; speedup 1.0000x reference)
//
#include <hip/hip_runtime.h>

#define B_SZ   32768
#define D_INN  512
#define D_CODE 128
#define HID    256
#define K_CB   8192
#define L_LVL  4

// ---------------------------------------------------------------------------
// block-wide float sum -> one f64 atomicAdd
// ---------------------------------------------------------------------------
__device__ inline void block_atomic_add32(double* acc, float v) {
    #pragma unroll
    for (int off = 32; off >= 1; off >>= 1) v += __shfl_down(v, off);
    __shared__ float wred[4];
    int lane = threadIdx.x & 63, wid = threadIdx.x >> 6;
    if (lane == 0) wred[wid] = v;
    __syncthreads();
    if (threadIdx.x == 0) {
        float s = wred[0] + wred[1] + wred[2] + wred[3];
        atomicAdd(acc, (double)s);
    }
}

// ---------------------------------------------------------------------------
// Tiled f32 GEMM for encoder/decoder: accumulator carried across k0-tiles ->
// per-C-element SINGLE sequential FMA chain over k (bit-exact class, r1==r4).
// DO NOT restructure the k-chain: codes correctness depends on it.
// ---------------------------------------------------------------------------
template<bool RELU, bool LOSS>
__global__ __launch_bounds__(256) void gemm32_kernel(
    const float* __restrict__ A, const float* __restrict__ W,
    const float* __restrict__ bias, float* __restrict__ C,
    const float* __restrict__ X, double* __restrict__ loss_acc,
    int M, int K, int N)
{
    __shared__ float As[32][68];
    __shared__ float Ws[32][68];
    const int tx = threadIdx.x & 15, ty = threadIdx.x >> 4;
    const int rowBase = blockIdx.x * 64;
    const int colBase = blockIdx.y * 64;

    float acc[4][4] = {};

    for (int k0 = 0; k0 < K; k0 += 32) {
        int f = threadIdx.x;
        #pragma unroll
        for (int it = 0; it < 2; ++it, f += 256) {
            int r = f >> 3, k4 = f & 7;
            float4 v = *(const float4*)&A[(size_t)(rowBase + r) * K + k0 + k4 * 4];
            As[k4 * 4 + 0][r] = v.x;
            As[k4 * 4 + 1][r] = v.y;
            As[k4 * 4 + 2][r] = v.z;
            As[k4 * 4 + 3][r] = v.w;
        }
        f = threadIdx.x;
        #pragma unroll
        for (int it = 0; it < 2; ++it, f += 256) {
            int kk = f >> 4, n4 = f & 15;
            float4 v = *(const float4*)&W[(size_t)(k0 + kk) * N + colBase + n4 * 4];
            *(float4*)&Ws[kk][n4 * 4] = v;
        }
        __syncthreads();
        #pragma unroll 8
        for (int kk = 0; kk < 32; ++kk) {
            float a[4], w[4];
            #pragma unroll
            for (int i = 0; i < 4; ++i) a[i] = As[kk][ty * 4 + i];
            #pragma unroll
            for (int j = 0; j < 4; ++j) w[j] = Ws[kk][tx * 4 + j];
            #pragma unroll
            for (int i = 0; i < 4; ++i)
                #pragma unroll
                for (int j = 0; j < 4; ++j)
                    acc[i][j] = fmaf(a[i], w[j], acc[i][j]);
        }
        __syncthreads();
    }

    float lsum = 0.f;
    #pragma unroll
    for (int i = 0; i < 4; ++i) {
        int row = rowBase + ty * 4 + i;
        #pragma unroll
        for (int j = 0; j < 4; ++j) {
            int col = colBase + tx * 4 + j;
            float c = __fadd_rn(acc[i][j], bias[col]);
            if (RELU) c = fmaxf(c, 0.f);
            C[(size_t)row * N + col] = c;
            if (LOSS) {
                float d = c - X[(size_t)row * N + col];
                lsum = fmaf(d, d, lsum);
            }
        }
    }
    if (LOSS) block_atomic_add32(loss_acc, lsum);
}

// ---------------------------------------------------------------------------
// numpy SIMD pairwise sum of squares, n=128 (bit-exact model — DO NOT CHANGE)
// ---------------------------------------------------------------------------
__global__ __launch_bounds__(256) void sqsum_npsimd_kernel(
    const float* __restrict__ p, float* __restrict__ out, int nrows)
{
    int row = blockIdx.x * 256 + threadIdx.x;
    if (row >= nrows) return;
    const float* a = p + (size_t)row * 128;

    float S[16];
    #pragma unroll
    for (int l = 0; l < 16; ++l) {
        float t0 = __fmul_rn(a[l],        a[l]);
        float t1 = __fmul_rn(a[16 + l],   a[16 + l]);
        float t2 = __fmul_rn(a[32 + l],   a[32 + l]);
        float t3 = __fmul_rn(a[48 + l],   a[48 + l]);
        float t4 = __fmul_rn(a[64 + l],   a[64 + l]);
        float t5 = __fmul_rn(a[80 + l],   a[80 + l]);
        float t6 = __fmul_rn(a[96 + l],   a[96 + l]);
        float t7 = __fmul_rn(a[112 + l],  a[112 + l]);
        float p01 = __fadd_rn(t0, t1);
        float p23 = __fadd_rn(t2, t3);
        float p45 = __fadd_rn(t4, t5);
        float p67 = __fadd_rn(t6, t7);
        S[l] = __fadd_rn(__fadd_rn(p01, p23), __fadd_rn(p45, p67));
    }
    float u[8];
    #pragma unroll
    for (int l = 0; l < 8; ++l) u[l] = __fadd_rn(S[l], S[l + 8]);
    float v[4];
    #pragma unroll
    for (int l = 0; l < 4; ++l) v[l] = __fadd_rn(u[l], u[l + 4]);
    float w0 = __fadd_rn(v[0], v[2]);
    float w1 = __fadd_rn(v[1], v[3]);
    out[row] = __fadd_rn(w0, w1);
}

// ---------------------------------------------------------------------------
// np distance scan + argmin, 4x8 micro-tile, 64 rows x 128 codes per block
// (grid = 512 blocks -> 2 blocks/CU), LDS = 67584 B (r18-proven size):
//   Rs[64][132] full-k staged once; Cs[128][66] k-half restaged per phase.
// dot[4][8] persists across phases -> per-(row,code) fmaf chain BIT-IDENTICAL
// (k ascending 0..127, _rn unfused epilogue, first-index ties).
// ---------------------------------------------------------------------------
__global__ __launch_bounds__(256) void quant_np_kernel(
    const float* __restrict__ resid, const float* __restrict__ cb,
    const float* __restrict__ cnorm, const float* __restrict__ rnorm,
    int* __restrict__ idx_out, float* __restrict__ codes_f, int lvl)
{
    __shared__ float Rs[64][132];   // 33792 B, full k
    __shared__ float Cs[128][66];   // 33792 B, one 64-wide k-half
    const int tx = threadIdx.x & 15, ty = threadIdx.x >> 4;
    const int rowBase = blockIdx.x * 64;

    // stage rows full-k (r18-proven pattern)
    {
        int f = threadIdx.x;
        #pragma unroll
        for (int it = 0; it < 8; ++it, f += 256) {
            int r = f >> 5, k4 = f & 31;
            float4 v = *(const float4*)&resid[(size_t)(rowBase + r) * D_CODE + k4 * 4];
            *(float4*)&Rs[r][k4 * 4] = v;
        }
    }

    float rn_reg[4];
    #pragma unroll
    for (int i = 0; i < 4; ++i) rn_reg[i] = rnorm[rowBase + ty * 4 + i];

    float best[4];
    int   bidx[4];
    #pragma unroll
    for (int i = 0; i < 4; ++i) { best[i] = 3.0e38f; bidx[i] = 0x7FFFFFFF; }

    const int k4s = threadIdx.x & 15;   // Cs staging: k-chunk 0..15
    const int c0  = threadIdx.x >> 4;   // Cs staging: code 0..15

    for (int tile = 0; tile < K_CB / 128; ++tile) {
        // prefetch codebook norms for this tile (in flight during compute)
        float cnv[8];
        #pragma unroll
        for (int j = 0; j < 8; ++j) cnv[j] = cnorm[tile * 128 + tx + 16 * j];

        float dot[4][8] = {};
        #pragma unroll
        for (int ph = 0; ph < 2; ++ph) {
            __syncthreads();   // protect previous phase's Cs reads (+Rs on t0)
            #pragma unroll
            for (int it = 0; it < 8; ++it) {
                int c = c0 + 16 * it;
                float4 v = *(const float4*)&cb[((size_t)tile * 128 + c) * D_CODE
                                               + ph * 64 + k4s * 4];
                *(float4*)&Cs[c][k4s * 4] = v;
            }
            __syncthreads();

            #pragma unroll 4
            for (int k4 = 0; k4 < 16; ++k4) {
                float4 rv[4], cv[8];
                #pragma unroll
                for (int i = 0; i < 4; ++i)
                    rv[i] = *(const float4*)&Rs[ty * 4 + i][ph * 64 + k4 * 4];
                #pragma unroll
                for (int j = 0; j < 8; ++j)
                    cv[j] = *(const float4*)&Cs[tx + 16 * j][k4 * 4];
                #pragma unroll
                for (int i = 0; i < 4; ++i)
                    #pragma unroll
                    for (int j = 0; j < 8; ++j) {
                        dot[i][j] = fmaf(rv[i].x, cv[j].x, dot[i][j]);
                        dot[i][j] = fmaf(rv[i].y, cv[j].y, dot[i][j]);
                        dot[i][j] = fmaf(rv[i].z, cv[j].z, dot[i][j]);
                        dot[i][j] = fmaf(rv[i].w, cv[j].w, dot[i][j]);
                    }
            }
        }

        // binned epilogue (bit-exact model — DO NOT CHANGE)
        #pragma unroll
        for (int j = 0; j < 8; ++j) {
            int c = tile * 128 + tx + 16 * j;
            #pragma unroll
            for (int i = 0; i < 4; ++i) {
                float s_ = __fadd_rn(rn_reg[i], cnv[j]);  // fl(rn + cn)
                float td = __fmul_rn(2.0f, dot[i][j]);    // fl(2*dot) (exact)
                float d  = __fsub_rn(s_, td);             // fl(s - 2dot), unfused
                if (d < best[i] || (d == best[i] && c < bidx[i])) {
                    best[i] = d; bidx[i] = c;
                }
            }
        }
    }

    // merge across the 16 tx lanes (xor<=8 stays in group), first-index ties
    #pragma unroll
    for (int off = 8; off >= 1; off >>= 1) {
        #pragma unroll
        for (int i = 0; i < 4; ++i) {
            float d2 = __shfl_xor(best[i], off);
            int   i2 = __shfl_xor(bidx[i], off);
            if (d2 < best[i] || (d2 == best[i] && i2 < bidx[i])) {
                best[i] = d2; bidx[i] = i2;
            }
        }
    }
    if (tx == 0) {
        #pragma unroll
        for (int i = 0; i < 4; ++i) {
            int row = rowBase + ty * 4 + i;
            idx_out[row] = bidx[i];
            codes_f[(size_t)row * L_LVL + lvl] = (float)bidx[i];
        }
    }
}

// ---------------------------------------------------------------------------
// f32 per-level update (bit-exact model — DO NOT CHANGE):
// q=cb[idx]; d=fl(q-r); q_ste=fl(r+d); z_q=fl(z_q+q_ste); r=fl(r-q_ste)
// ---------------------------------------------------------------------------
__global__ __launch_bounds__(256) void quant_update(
    const float* __restrict__ cb, const int* __restrict__ idx,
    float* __restrict__ resid, float* __restrict__ z_q,
    double* __restrict__ loss_acc, int first)
{
    int e4 = blockIdx.x * 256 + threadIdx.x;
    int row = e4 >> 5, k4 = e4 & 31;
    int c = idx[row];
    float4 q = *(const float4*)&cb[(size_t)c * D_CODE + k4 * 4];
    float4 r = *(const float4*)&resid[(size_t)e4 * 4];

    float dx = __fsub_rn(q.x, r.x), dy = __fsub_rn(q.y, r.y);
    float dz = __fsub_rn(q.z, r.z), dw = __fsub_rn(q.w, r.w);
    float ls = dx * dx + dy * dy + dz * dz + dw * dw;   // loss: loose threshold

    float qsx = __fadd_rn(r.x, dx), qsy = __fadd_rn(r.y, dy);
    float qsz = __fadd_rn(r.z, dz), qsw = __fadd_rn(r.w, dw);

    float4 z;
    if (first) { z.x = qsx; z.y = qsy; z.z = qsz; z.w = qsw; }
    else {
        z = *(const float4*)&z_q[(size_t)e4 * 4];
        z.x = __fadd_rn(z.x, qsx); z.y = __fadd_rn(z.y, qsy);
        z.z = __fadd_rn(z.z, qsz); z.w = __fadd_rn(z.w, qsw);
    }
    *(float4*)&z_q[(size_t)e4 * 4] = z;

    float4 rn;
    rn.x = __fsub_rn(r.x, qsx); rn.y = __fsub_rn(r.y, qsy);
    rn.z = __fsub_rn(r.z, qsz); rn.w = __fsub_rn(r.w, qsw);
    *(float4*)&resid[(size_t)e4 * 4] = rn;

    block_atomic_add32(loss_acc, ls);
}

// ---------------------------------------------------------------------------
__global__ void finalize_kernel(const double* __restrict__ acc,
                                float* __restrict__ scalars)
{
    double q_sum = acc[0], rec_sum = acc[1];
    double cb_total = q_sum / (double)((size_t)B_SZ * D_CODE);
    double recon    = rec_sum / (double)((size_t)B_SZ * D_INN);
    scalars[0] = (float)cb_total;
    scalars[1] = (float)(0.25 * cb_total);
    scalars[2] = (float)recon;
    scalars[3] = (float)(cb_total + 0.25 * cb_total + recon);
}

// ---------------------------------------------------------------------------
extern "C" void kernel_launch(void* const* d_in, const int* in_sizes, int n_in,
                              void* d_out, int out_size, void* d_ws, size_t ws_size,
                              hipStream_t stream)
{
    const float* x       = (const float*)d_in[0];
    const float* enc_w1  = (const float*)d_in[1];
    const float* enc_b1  = (const float*)d_in[2];
    const float* enc_w2  = (const float*)d_in[3];
    const float* enc_b2  = (const float*)d_in[4];
    const float* cbooks  = (const float*)d_in[5];
    const float* dec_w1  = (const float*)d_in[6];
    const float* dec_b1  = (const float*)d_in[7];
    const float* dec_w2  = (const float*)d_in[8];
    const float* dec_b2  = (const float*)d_in[9];

    float* out     = (float*)d_out;
    float* recon   = out;                                   // B * D_IN
    float* z_q     = out + (size_t)B_SZ * D_INN;            // B * D_CODE
    float* codes_f = z_q + (size_t)B_SZ * D_CODE;           // B * L
    float* scalars = codes_f + (size_t)B_SZ * L_LVL;        // 4

    const size_t MB = 1u << 20;
    char*   ws    = (char*)d_ws;
    double* acc   = (double*)ws;                            // 2 doubles @ 0
    int*    idx   = (int*)(ws + 4096);                      // B ints
    float*  cn    = (float*)(ws + 4096 + 131072);           // L*K floats
    float*  rn    = (float*)(ws + 4096 + 131072 + 131072);  // B floats
    float*  z1    = (float*)(ws + 1 * MB);                  // B*HID   = 32MB
    float*  resid = (float*)(ws + 33 * MB);                 // B*D_CODE= 16MB
    float*  h_dec = (float*)(ws + 49 * MB);                 // B*HID   = 32MB
    // total 81MB

    hipMemsetAsync(acc, 0, 2 * sizeof(double), stream);

    // encoder: single-sequential-FMA-chain tiled GEMM (exact-class z_e)
    gemm32_kernel<true, false><<<dim3(B_SZ / 64, HID / 64), 256, 0, stream>>>(
        x, enc_w1, enc_b1, z1, nullptr, nullptr, B_SZ, D_INN, HID);
    gemm32_kernel<false, false><<<dim3(B_SZ / 64, D_CODE / 64), 256, 0, stream>>>(
        z1, enc_w2, enc_b2, resid, nullptr, nullptr, B_SZ, HID, D_CODE);

    // codebook norms (numpy AVX-512 SIMD pairwise, one pass)
    sqsum_npsimd_kernel<<<(L_LVL * K_CB + 255) / 256, 256, 0, stream>>>(
        cbooks, cn, L_LVL * K_CB);

    // residual quantization (binned np formula; 4x8-tiled k-split scan)
    for (int lvl = 0; lvl < L_LVL; ++lvl) {
        const float* cb_l = cbooks + (size_t)lvl * K_CB * D_CODE;
        sqsum_npsimd_kernel<<<(B_SZ + 255) / 256, 256, 0, stream>>>(resid, rn, B_SZ);
        quant_np_kernel<<<B_SZ / 64, 256, 0, stream>>>(
            resid, cb_l, cn + (size_t)lvl * K_CB, rn, idx, codes_f, lvl);
        quant_update<<<(B_SZ * (D_CODE / 4)) / 256, 256, 0, stream>>>(
            cb_l, idx, resid, z_q, acc, lvl == 0 ? 1 : 0);
    }

    // decoder
    gemm32_kernel<true, false><<<dim3(B_SZ / 64, HID / 64), 256, 0, stream>>>(
        z_q, dec_w1, dec_b1, h_dec, nullptr, nullptr, B_SZ, D_CODE, HID);
    gemm32_kernel<false, true><<<dim3(B_SZ / 64, D_INN / 64), 256, 0, stream>>>(
        h_dec, dec_w2, dec_b2, recon, x, acc + 1, B_SZ, HID, D_INN);

    finalize_kernel<<<1, 1, 0, stream>>>(acc, scalars);
}

// Round 22
// 4726.058 us; speedup vs baseline: 1.0444x; 1.0444x over previous
//
#include <hip/hip_runtime.h>

#define B_SZ   32768
#define D_INN  512
#define D_CODE 128
#define HID    256
#define K_CB   8192
#define L_LVL  4

// ---------------------------------------------------------------------------
// block-wide float sum -> one f64 atomicAdd
// ---------------------------------------------------------------------------
__device__ inline void block_atomic_add32(double* acc, float v) {
    #pragma unroll
    for (int off = 32; off >= 1; off >>= 1) v += __shfl_down(v, off);
    __shared__ float wred[4];
    int lane = threadIdx.x & 63, wid = threadIdx.x >> 6;
    if (lane == 0) wred[wid] = v;
    __syncthreads();
    if (threadIdx.x == 0) {
        float s = wred[0] + wred[1] + wred[2] + wred[3];
        atomicAdd(acc, (double)s);
    }
}

// ---------------------------------------------------------------------------
// Tiled f32 GEMM for encoder/decoder: accumulator carried across k0-tiles ->
// per-C-element SINGLE sequential FMA chain over k (bit-exact class, r1==r4).
// DO NOT restructure the k-chain: codes correctness depends on it.
// ---------------------------------------------------------------------------
template<bool RELU, bool LOSS>
__global__ __launch_bounds__(256) void gemm32_kernel(
    const float* __restrict__ A, const float* __restrict__ W,
    const float* __restrict__ bias, float* __restrict__ C,
    const float* __restrict__ X, double* __restrict__ loss_acc,
    int M, int K, int N)
{
    __shared__ float As[32][68];
    __shared__ float Ws[32][68];
    const int tx = threadIdx.x & 15, ty = threadIdx.x >> 4;
    const int rowBase = blockIdx.x * 64;
    const int colBase = blockIdx.y * 64;

    float acc[4][4] = {};

    for (int k0 = 0; k0 < K; k0 += 32) {
        int f = threadIdx.x;
        #pragma unroll
        for (int it = 0; it < 2; ++it, f += 256) {
            int r = f >> 3, k4 = f & 7;
            float4 v = *(const float4*)&A[(size_t)(rowBase + r) * K + k0 + k4 * 4];
            As[k4 * 4 + 0][r] = v.x;
            As[k4 * 4 + 1][r] = v.y;
            As[k4 * 4 + 2][r] = v.z;
            As[k4 * 4 + 3][r] = v.w;
        }
        f = threadIdx.x;
        #pragma unroll
        for (int it = 0; it < 2; ++it, f += 256) {
            int kk = f >> 4, n4 = f & 15;
            float4 v = *(const float4*)&W[(size_t)(k0 + kk) * N + colBase + n4 * 4];
            *(float4*)&Ws[kk][n4 * 4] = v;
        }
        __syncthreads();
        #pragma unroll 8
        for (int kk = 0; kk < 32; ++kk) {
            float a[4], w[4];
            #pragma unroll
            for (int i = 0; i < 4; ++i) a[i] = As[kk][ty * 4 + i];
            #pragma unroll
            for (int j = 0; j < 4; ++j) w[j] = Ws[kk][tx * 4 + j];
            #pragma unroll
            for (int i = 0; i < 4; ++i)
                #pragma unroll
                for (int j = 0; j < 4; ++j)
                    acc[i][j] = fmaf(a[i], w[j], acc[i][j]);
        }
        __syncthreads();
    }

    float lsum = 0.f;
    #pragma unroll
    for (int i = 0; i < 4; ++i) {
        int row = rowBase + ty * 4 + i;
        #pragma unroll
        for (int j = 0; j < 4; ++j) {
            int col = colBase + tx * 4 + j;
            float c = __fadd_rn(acc[i][j], bias[col]);
            if (RELU) c = fmaxf(c, 0.f);
            C[(size_t)row * N + col] = c;
            if (LOSS) {
                float d = c - X[(size_t)row * N + col];
                lsum = fmaf(d, d, lsum);
            }
        }
    }
    if (LOSS) block_atomic_add32(loss_acc, lsum);
}

// ---------------------------------------------------------------------------
// numpy SIMD pairwise sum of squares, n=128 (bit-exact model — DO NOT CHANGE)
// ---------------------------------------------------------------------------
__global__ __launch_bounds__(256) void sqsum_npsimd_kernel(
    const float* __restrict__ p, float* __restrict__ out, int nrows)
{
    int row = blockIdx.x * 256 + threadIdx.x;
    if (row >= nrows) return;
    const float* a = p + (size_t)row * 128;

    float S[16];
    #pragma unroll
    for (int l = 0; l < 16; ++l) {
        float t0 = __fmul_rn(a[l],        a[l]);
        float t1 = __fmul_rn(a[16 + l],   a[16 + l]);
        float t2 = __fmul_rn(a[32 + l],   a[32 + l]);
        float t3 = __fmul_rn(a[48 + l],   a[48 + l]);
        float t4 = __fmul_rn(a[64 + l],   a[64 + l]);
        float t5 = __fmul_rn(a[80 + l],   a[80 + l]);
        float t6 = __fmul_rn(a[96 + l],   a[96 + l]);
        float t7 = __fmul_rn(a[112 + l],  a[112 + l]);
        float p01 = __fadd_rn(t0, t1);
        float p23 = __fadd_rn(t2, t3);
        float p45 = __fadd_rn(t4, t5);
        float p67 = __fadd_rn(t6, t7);
        S[l] = __fadd_rn(__fadd_rn(p01, p23), __fadd_rn(p45, p67));
    }
    float u[8];
    #pragma unroll
    for (int l = 0; l < 8; ++l) u[l] = __fadd_rn(S[l], S[l + 8]);
    float v[4];
    #pragma unroll
    for (int l = 0; l < 4; ++l) v[l] = __fadd_rn(u[l], u[l + 4]);
    float w0 = __fadd_rn(v[0], v[2]);
    float w1 = __fadd_rn(v[1], v[3]);
    out[row] = __fadd_rn(w0, w1);
}

// ---------------------------------------------------------------------------
// np distance scan + argmin, 4x8 micro-tile, 64 rows x 128 codes per block
// (grid = 512 blocks -> 2 blocks/CU).  LDS = 68608 B:
//   Rs[64][132] full-k staged once; Cs[128][68] k-half restaged per phase.
// Stride 68 == 4 mod 32 -> free 2-way bank aliasing (the r21 stride-66
// regression produced 1.7e7 conflicts; this is the fix).
// dot[4][8] persists across phases -> per-(row,code) fmaf chain BIT-IDENTICAL
// (k ascending 0..127, _rn unfused epilogue, first-index ties).
// ---------------------------------------------------------------------------
__global__ __launch_bounds__(256) void quant_np_kernel(
    const float* __restrict__ resid, const float* __restrict__ cb,
    const float* __restrict__ cnorm, const float* __restrict__ rnorm,
    int* __restrict__ idx_out, float* __restrict__ codes_f, int lvl)
{
    __shared__ float Rs[64][132];   // 33792 B, full k
    __shared__ float Cs[128][68];   // 34816 B, one 64-wide k-half (stride%32==4)
    const int tx = threadIdx.x & 15, ty = threadIdx.x >> 4;
    const int rowBase = blockIdx.x * 64;

    // stage rows full-k (r18-proven pattern)
    {
        int f = threadIdx.x;
        #pragma unroll
        for (int it = 0; it < 8; ++it, f += 256) {
            int r = f >> 5, k4 = f & 31;
            float4 v = *(const float4*)&resid[(size_t)(rowBase + r) * D_CODE + k4 * 4];
            *(float4*)&Rs[r][k4 * 4] = v;
        }
    }

    float rn_reg[4];
    #pragma unroll
    for (int i = 0; i < 4; ++i) rn_reg[i] = rnorm[rowBase + ty * 4 + i];

    float best[4];
    int   bidx[4];
    #pragma unroll
    for (int i = 0; i < 4; ++i) { best[i] = 3.0e38f; bidx[i] = 0x7FFFFFFF; }

    const int k4s = threadIdx.x & 15;   // Cs staging: k-chunk 0..15
    const int c0  = threadIdx.x >> 4;   // Cs staging: code 0..15

    for (int tile = 0; tile < K_CB / 128; ++tile) {
        // prefetch codebook norms for this tile (in flight during compute)
        float cnv[8];
        #pragma unroll
        for (int j = 0; j < 8; ++j) cnv[j] = cnorm[tile * 128 + tx + 16 * j];

        float dot[4][8] = {};
        #pragma unroll
        for (int ph = 0; ph < 2; ++ph) {
            __syncthreads();   // protect previous phase's Cs reads (+Rs on t0)
            #pragma unroll
            for (int it = 0; it < 8; ++it) {
                int c = c0 + 16 * it;
                float4 v = *(const float4*)&cb[((size_t)tile * 128 + c) * D_CODE
                                               + ph * 64 + k4s * 4];
                *(float4*)&Cs[c][k4s * 4] = v;
            }
            __syncthreads();

            #pragma unroll 4
            for (int k4 = 0; k4 < 16; ++k4) {
                float4 rv[4], cv[8];
                #pragma unroll
                for (int i = 0; i < 4; ++i)
                    rv[i] = *(const float4*)&Rs[ty * 4 + i][ph * 64 + k4 * 4];
                #pragma unroll
                for (int j = 0; j < 8; ++j)
                    cv[j] = *(const float4*)&Cs[tx + 16 * j][k4 * 4];
                #pragma unroll
                for (int i = 0; i < 4; ++i)
                    #pragma unroll
                    for (int j = 0; j < 8; ++j) {
                        dot[i][j] = fmaf(rv[i].x, cv[j].x, dot[i][j]);
                        dot[i][j] = fmaf(rv[i].y, cv[j].y, dot[i][j]);
                        dot[i][j] = fmaf(rv[i].z, cv[j].z, dot[i][j]);
                        dot[i][j] = fmaf(rv[i].w, cv[j].w, dot[i][j]);
                    }
            }
        }

        // binned epilogue (bit-exact model — DO NOT CHANGE)
        #pragma unroll
        for (int j = 0; j < 8; ++j) {
            int c = tile * 128 + tx + 16 * j;
            #pragma unroll
            for (int i = 0; i < 4; ++i) {
                float s_ = __fadd_rn(rn_reg[i], cnv[j]);  // fl(rn + cn)
                float td = __fmul_rn(2.0f, dot[i][j]);    // fl(2*dot) (exact)
                float d  = __fsub_rn(s_, td);             // fl(s - 2dot), unfused
                if (d < best[i] || (d == best[i] && c < bidx[i])) {
                    best[i] = d; bidx[i] = c;
                }
            }
        }
    }

    // merge across the 16 tx lanes (xor<=8 stays in group), first-index ties
    #pragma unroll
    for (int off = 8; off >= 1; off >>= 1) {
        #pragma unroll
        for (int i = 0; i < 4; ++i) {
            float d2 = __shfl_xor(best[i], off);
            int   i2 = __shfl_xor(bidx[i], off);
            if (d2 < best[i] || (d2 == best[i] && i2 < bidx[i])) {
                best[i] = d2; bidx[i] = i2;
            }
        }
    }
    if (tx == 0) {
        #pragma unroll
        for (int i = 0; i < 4; ++i) {
            int row = rowBase + ty * 4 + i;
            idx_out[row] = bidx[i];
            codes_f[(size_t)row * L_LVL + lvl] = (float)bidx[i];
        }
    }
}

// ---------------------------------------------------------------------------
// f32 per-level update (bit-exact model — DO NOT CHANGE):
// q=cb[idx]; d=fl(q-r); q_ste=fl(r+d); z_q=fl(z_q+q_ste); r=fl(r-q_ste)
// ---------------------------------------------------------------------------
__global__ __launch_bounds__(256) void quant_update(
    const float* __restrict__ cb, const int* __restrict__ idx,
    float* __restrict__ resid, float* __restrict__ z_q,
    double* __restrict__ loss_acc, int first)
{
    int e4 = blockIdx.x * 256 + threadIdx.x;
    int row = e4 >> 5, k4 = e4 & 31;
    int c = idx[row];
    float4 q = *(const float4*)&cb[(size_t)c * D_CODE + k4 * 4];
    float4 r = *(const float4*)&resid[(size_t)e4 * 4];

    float dx = __fsub_rn(q.x, r.x), dy = __fsub_rn(q.y, r.y);
    float dz = __fsub_rn(q.z, r.z), dw = __fsub_rn(q.w, r.w);
    float ls = dx * dx + dy * dy + dz * dz + dw * dw;   // loss: loose threshold

    float qsx = __fadd_rn(r.x, dx), qsy = __fadd_rn(r.y, dy);
    float qsz = __fadd_rn(r.z, dz), qsw = __fadd_rn(r.w, dw);

    float4 z;
    if (first) { z.x = qsx; z.y = qsy; z.z = qsz; z.w = qsw; }
    else {
        z = *(const float4*)&z_q[(size_t)e4 * 4];
        z.x = __fadd_rn(z.x, qsx); z.y = __fadd_rn(z.y, qsy);
        z.z = __fadd_rn(z.z, qsz); z.w = __fadd_rn(z.w, qsw);
    }
    *(float4*)&z_q[(size_t)e4 * 4] = z;

    float4 rn;
    rn.x = __fsub_rn(r.x, qsx); rn.y = __fsub_rn(r.y, qsy);
    rn.z = __fsub_rn(r.z, qsz); rn.w = __fsub_rn(r.w, qsw);
    *(float4*)&resid[(size_t)e4 * 4] = rn;

    block_atomic_add32(loss_acc, ls);
}

// ---------------------------------------------------------------------------
__global__ void finalize_kernel(const double* __restrict__ acc,
                                float* __restrict__ scalars)
{
    double q_sum = acc[0], rec_sum = acc[1];
    double cb_total = q_sum / (double)((size_t)B_SZ * D_CODE);
    double recon    = rec_sum / (double)((size_t)B_SZ * D_INN);
    scalars[0] = (float)cb_total;
    scalars[1] = (float)(0.25 * cb_total);
    scalars[2] = (float)recon;
    scalars[3] = (float)(cb_total + 0.25 * cb_total + recon);
}

// ---------------------------------------------------------------------------
extern "C" void kernel_launch(void* const* d_in, const int* in_sizes, int n_in,
                              void* d_out, int out_size, void* d_ws, size_t ws_size,
                              hipStream_t stream)
{
    const float* x       = (const float*)d_in[0];
    const float* enc_w1  = (const float*)d_in[1];
    const float* enc_b1  = (const float*)d_in[2];
    const float* enc_w2  = (const float*)d_in[3];
    const float* enc_b2  = (const float*)d_in[4];
    const float* cbooks  = (const float*)d_in[5];
    const float* dec_w1  = (const float*)d_in[6];
    const float* dec_b1  = (const float*)d_in[7];
    const float* dec_w2  = (const float*)d_in[8];
    const float* dec_b2  = (const float*)d_in[9];

    float* out     = (float*)d_out;
    float* recon   = out;                                   // B * D_IN
    float* z_q     = out + (size_t)B_SZ * D_INN;            // B * D_CODE
    float* codes_f = z_q + (size_t)B_SZ * D_CODE;           // B * L
    float* scalars = codes_f + (size_t)B_SZ * L_LVL;        // 4

    const size_t MB = 1u << 20;
    char*   ws    = (char*)d_ws;
    double* acc   = (double*)ws;                            // 2 doubles @ 0
    int*    idx   = (int*)(ws + 4096);                      // B ints
    float*  cn    = (float*)(ws + 4096 + 131072);           // L*K floats
    float*  rn    = (float*)(ws + 4096 + 131072 + 131072);  // B floats
    float*  z1    = (float*)(ws + 1 * MB);                  // B*HID   = 32MB
    float*  resid = (float*)(ws + 33 * MB);                 // B*D_CODE= 16MB
    float*  h_dec = (float*)(ws + 49 * MB);                 // B*HID   = 32MB
    // total 81MB

    hipMemsetAsync(acc, 0, 2 * sizeof(double), stream);

    // encoder: single-sequential-FMA-chain tiled GEMM (exact-class z_e)
    gemm32_kernel<true, false><<<dim3(B_SZ / 64, HID / 64), 256, 0, stream>>>(
        x, enc_w1, enc_b1, z1, nullptr, nullptr, B_SZ, D_INN, HID);
    gemm32_kernel<false, false><<<dim3(B_SZ / 64, D_CODE / 64), 256, 0, stream>>>(
        z1, enc_w2, enc_b2, resid, nullptr, nullptr, B_SZ, HID, D_CODE);

    // codebook norms (numpy AVX-512 SIMD pairwise, one pass)
    sqsum_npsimd_kernel<<<(L_LVL * K_CB + 255) / 256, 256, 0, stream>>>(
        cbooks, cn, L_LVL * K_CB);

    // residual quantization (binned np formula; 4x8-tiled k-split scan)
    for (int lvl = 0; lvl < L_LVL; ++lvl) {
        const float* cb_l = cbooks + (size_t)lvl * K_CB * D_CODE;
        sqsum_npsimd_kernel<<<(B_SZ + 255) / 256, 256, 0, stream>>>(resid, rn, B_SZ);
        quant_np_kernel<<<B_SZ / 64, 256, 0, stream>>>(
            resid, cb_l, cn + (size_t)lvl * K_CB, rn, idx, codes_f, lvl);
        quant_update<<<(B_SZ * (D_CODE / 4)) / 256, 256, 0, stream>>>(
            cb_l, idx, resid, z_q, acc, lvl == 0 ? 1 : 0);
    }

    // decoder
    gemm32_kernel<true, false><<<dim3(B_SZ / 64, HID / 64), 256, 0, stream>>>(
        z_q, dec_w1, dec_b1, h_dec, nullptr, nullptr, B_SZ, D_CODE, HID);
    gemm32_kernel<false, true><<<dim3(B_SZ / 64, D_INN / 64), 256, 0, stream>>>(
        h_dec, dec_w2, dec_b2, recon, x, acc + 1, B_SZ, HID, D_INN);

    finalize_kernel<<<1, 1, 0, stream>>>(acc, scalars);
}